// Round 14
// baseline (212.946 us; speedup 1.0000x reference)
//
#include <hip/hip_runtime.h>

// Soft product quantizer — builtin-MFMA + probe-calibrated layout, 8-wave blocks.
// z:(8,384,32,32) f32, C:(2048,384) f32. 4096 pairs (n,n+4096) x K=8, d=48, M=2048.
// s = 2<x,c> - |c|^2 (x^2 cancels; |s| small -> no max-subtract).
// Probe MFMAs label every D-slot (mS = A-row label, rS = B-col label): exact
// under ANY bijective fragment layout since real GEMMs use the same addressing.
// Pass1: S -> Z,T via LDS atomics keyed rS. Pass2: S again -> P scatter at
// measured coords -> O = P*C (same mfma recipe) -> store at (mS, dt*16+rS).
// 8 waves: rg=wv&3 (16-pair row group), ch=wv>>2 (mt half: codes 32ch..+32 of
// each 64-tile). O partials combined via LDS obuf. 2 blocks/CU, 4 waves/SIMD.

typedef __attribute__((ext_vector_type(8))) short short8;
typedef __attribute__((ext_vector_type(4))) float f32x4;

#define Z_BCH   (384*1024)
#define JSD_IDX 3145728

__device__ __forceinline__ f32x4 mfma32(short8 a, short8 b, f32x4 c) {
    return __builtin_amdgcn_mfma_f32_16x16x32_bf16(a, b, c, 0, 0, 0);
}
__device__ __forceinline__ unsigned short f2bf(float x) {
    unsigned u = __float_as_uint(x);
    u += 0x7FFF + ((u >> 16) & 1);          // RNE
    return (unsigned short)(u >> 16);
}
__device__ __forceinline__ unsigned pk2bf(float a, float b) {
    return (unsigned)f2bf(a) | ((unsigned)f2bf(b) << 16);
}
__device__ __forceinline__ float bf2f(unsigned short h) {
    return __uint_as_float(((unsigned)h) << 16);
}

// LDS (bytes):
//  cs  [64][72] u16 @0      (9216)  codes: d0..47, 48/49=-c2/2 hi/lo, 50..63=0
//  ct  [48][72] u16 @9216   (6912)  C^T [d][m]
//  plds per-wave [32][40] u16 @16128+wv*2560 (20480)  P rows: 16p+16q, 32 cols
//  @36608 ztP[64] ttP ztQ ttQ (1024) | @37632 ipzP ipzQ (512)
//  @38144 entP entQ (512) | @38656 misc[8] (32) -> 38688 total
//  xs [128][72] u16 @0 (18432, prologue overlay) | obuf [4][32][48] f32 @0 (epilogue)
__global__ __launch_bounds__(512, 4)
void pq_mfb8(const float* __restrict__ Zin, const float* __restrict__ Cb,
             float* __restrict__ Out)
{
    __shared__ __align__(16) unsigned char smem[38688];
    unsigned short* cs = (unsigned short*)smem;
    unsigned short* ct = (unsigned short*)(smem + 9216);
    unsigned short* xs = (unsigned short*)smem;
    float* ztP  = (float*)(smem + 36608);
    float* ttP  = (float*)(smem + 36864);
    float* ztQ  = (float*)(smem + 37120);
    float* ttQ  = (float*)(smem + 37376);
    float* ipzP = (float*)(smem + 37632);
    float* ipzQ = (float*)(smem + 37888);
    float* entP = (float*)(smem + 38144);
    float* entQ = (float*)(smem + 38400);
    float* misc = (float*)(smem + 38656);
    float* obuf = (float*)smem;            // [4][32][48] f32, epilogue reuse

    const int tid  = threadIdx.x;
    const int lane = tid & 63;
    const int wv   = tid >> 6;          // 0..7
    const int rg   = wv & 3;            // pair-row group (16 pairs)
    const int chw  = wv >> 2;           // code half: mt in {2chw, 2chw+1}
    const int lr   = lane & 15;
    const int lg   = lane >> 4;
    const int pg   = blockIdx.x & 63;   // 64 pair-groups (64 pairs each)
    const int k    = blockIdx.x >> 6;   // subspace

    unsigned short* plds = (unsigned short*)(smem + 16128 + wv*2560);   // [32][40]

    // ---------- layout probes (builtin MFMA, register-only, exact) ----------
    short8 av, on;
#pragma unroll
    for (int i = 0; i < 8; ++i) { av[i] = (short)f2bf((float)lr); on[i] = (short)0x3F80; }
    f32x4 zf4 = {0.f,0.f,0.f,0.f};
    f32x4 dm = mfma32(av, on, zf4);     // slot j -> A-row label
    f32x4 dr = mfma32(on, av, zf4);     // slot j -> B-col label
    int mS[4], rS[4];
#pragma unroll
    for (int j = 0; j < 4; ++j) {
        mS[j] = ((int)(dm[j]*0.03125f + 0.5f)) & 15;
        rS[j] = ((int)(dr[j]*0.03125f + 0.5f)) & 15;
    }

    // ---------- prologue: zero stats + xs; x -> xs -> register B-frags ----------
    if (tid < 256) ((float*)(smem + 36608))[tid] = 0.f;    // ztP..ttQ
    for (int i = tid; i < 4608; i += 512) ((unsigned*)smem)[i] = 0u;   // zero xs
    __syncthreads();
    for (int i = tid; i < 6144; i += 512) {                // 128 rows x 48 dims
        int row = i & 127, d = i >> 7;
        int n = pg*64 + (row & 63) + ((row & 64) ? 4096 : 0);
        xs[row*72 + d] = f2bf(Zin[(size_t)(n >> 10)*Z_BCH + (k*48 + d)*1024 + (n & 1023)]);
    }
    if (tid < 128) { xs[tid*72 + 48] = 0x3F80; xs[tid*72 + 49] = 0x3F80; }
    __syncthreads();
    short8 xf[2][2];   // [p/q][k-half]; wave rows: p = rg*16+lr, q = +64
#pragma unroll
    for (int kh = 0; kh < 2; ++kh) {
        xf[0][kh] = *(const short8*)(xs + (rg*16 + lr)*72 + kh*32 + lg*8);
        xf[1][kh] = *(const short8*)(xs + (64 + rg*16 + lr)*72 + kh*32 + lg*8);
    }
    __syncthreads();   // xs region reusable (cs/ct/plds overlay)

    // staging roles: tid<256 -> cs data; tid>=256 -> ct scatter + c2 pads
    const int sm = tid & 63, p8 = (tid >> 6) & 3;
    auto stage = [&](int m0, bool doCT) {
        if (tid < 256) {
            const float4* crow = (const float4*)(Cb + (size_t)(m0 + sm)*384 + k*48);
            float4 va = crow[p8*3+0], vb = crow[p8*3+1], vc = crow[p8*3+2];
            const int d0 = p8*12;
            *(uint2*)(cs + sm*72 + d0 + 0) = make_uint2(pk2bf(va.x, va.y), pk2bf(va.z, va.w));
            *(uint2*)(cs + sm*72 + d0 + 4) = make_uint2(pk2bf(vb.x, vb.y), pk2bf(vb.z, vb.w));
            *(uint2*)(cs + sm*72 + d0 + 8) = make_uint2(pk2bf(vc.x, vc.y), pk2bf(vc.z, vc.w));
        } else {
            if (doCT) {
                const float4* crow = (const float4*)(Cb + (size_t)(m0 + sm)*384 + k*48);
                float4 va = crow[p8*3+0], vb = crow[p8*3+1], vc = crow[p8*3+2];
                const int d0 = p8*12;
                ct[(d0+ 0)*72 + sm] = f2bf(va.x);
                ct[(d0+ 1)*72 + sm] = f2bf(va.y);
                ct[(d0+ 2)*72 + sm] = f2bf(va.z);
                ct[(d0+ 3)*72 + sm] = f2bf(va.w);
                ct[(d0+ 4)*72 + sm] = f2bf(vb.x);
                ct[(d0+ 5)*72 + sm] = f2bf(vb.y);
                ct[(d0+ 6)*72 + sm] = f2bf(vb.z);
                ct[(d0+ 7)*72 + sm] = f2bf(vb.w);
                ct[(d0+ 8)*72 + sm] = f2bf(vc.x);
                ct[(d0+ 9)*72 + sm] = f2bf(vc.y);
                ct[(d0+10)*72 + sm] = f2bf(vc.z);
                ct[(d0+11)*72 + sm] = f2bf(vc.w);
            }
            if ((tid & 255) < 64) {   // c2 pads (cols 48..63) for row tid&63
                const int r = tid & 63;
                const float4* cr2 = (const float4*)(Cb + (size_t)(m0 + r)*384 + k*48);
                float c2 = 0.f;
#pragma unroll
                for (int i = 0; i < 12; ++i) {
                    float4 v = cr2[i];
                    c2 += v.x*v.x + v.y*v.y + v.z*v.z + v.w*v.w;
                }
                float mh = -0.5f*c2;
                unsigned short hi = f2bf(mh);
                unsigned short lo = f2bf(mh - bf2f(hi));
                *(uint2*)(cs + r*72 + 48) = make_uint2((unsigned)hi | ((unsigned)lo << 16), 0u);
                *(uint2*)(cs + r*72 + 52) = make_uint2(0u, 0u);
                *(uint2*)(cs + r*72 + 56) = make_uint2(0u, 0u);
                *(uint2*)(cs + r*72 + 60) = make_uint2(0u, 0u);
            }
        }
    };

    // ---------------- pass 1: softmax stats (per-slot, attribution-free) ----------------
    float zp[4] = {0,0,0,0}, tp[4] = {0,0,0,0}, zq[4] = {0,0,0,0}, tq[4] = {0,0,0,0};
#pragma unroll 1
    for (int t = 0; t < 32; ++t) {
        stage(t*64, false);
        __syncthreads();
#pragma unroll
        for (int lmt = 0; lmt < 2; ++lmt) {
            const int mt = chw*2 + lmt;
            short8 a0 = *(const short8*)(cs + (mt*16 + lr)*72 + lg*8);
            short8 a1 = *(const short8*)(cs + (mt*16 + lr)*72 + 32 + lg*8);
            f32x4 accP = {0.f,0.f,0.f,0.f}, accQ = {0.f,0.f,0.f,0.f};
            accP = mfma32(a0, xf[0][0], accP);
            accP = mfma32(a1, xf[0][1], accP);
            accQ = mfma32(a0, xf[1][0], accQ);
            accQ = mfma32(a1, xf[1][1], accQ);
#pragma unroll
            for (int j = 0; j < 4; ++j) {
                float sp = 2.f*accP[j], sq = 2.f*accQ[j];
                float e1 = __expf(sp), e2 = __expf(sq);
                zp[j] += e1; tp[j] = fmaf(e1, sp, tp[j]);
                zq[j] += e2; tq[j] = fmaf(e2, sq, tq[j]);
            }
        }
        __syncthreads();
    }
    // per-row totals via LDS atomics keyed by measured rS
#pragma unroll
    for (int j = 0; j < 4; ++j) {
        int r = rg*16 + rS[j];
        atomicAdd(ztP + r, zp[j]); atomicAdd(ttP + r, tp[j]);
        atomicAdd(ztQ + r, zq[j]); atomicAdd(ttQ + r, tq[j]);
    }
    __syncthreads();
    if (tid < 64) {
        float z1 = ztP[tid], t1 = ttP[tid];
        float z2 = ztQ[tid], t2 = ttQ[tid];
        float i1 = 1.f/z1, i2 = 1.f/z2;
        ipzP[tid] = i1; entP[tid] = t1*i1 - __logf(z1);
        ipzQ[tid] = i2; entQ[tid] = t2*i2 - __logf(z2);
    }
    __syncthreads();
    float izp_s[4], izq_s[4];
#pragma unroll
    for (int j = 0; j < 4; ++j) {
        izp_s[j] = ipzP[rg*16 + rS[j]];
        izq_s[j] = ipzQ[rg*16 + rS[j]];
    }

    // ---------------- pass 2: recompute S, P -> plds, O-MFMA (K=32), cross ----------------
    f32x4 Op[3], Oq[3];
#pragma unroll
    for (int dt = 0; dt < 3; ++dt) { Op[dt] = (f32x4){0.f,0.f,0.f,0.f}; Oq[dt] = (f32x4){0.f,0.f,0.f,0.f}; }
    float cross = 0.f;

#pragma unroll 1
    for (int t = 0; t < 32; ++t) {
        stage(t*64, true);
        __syncthreads();
#pragma unroll
        for (int lmt = 0; lmt < 2; ++lmt) {
            const int mt = chw*2 + lmt;
            short8 a0 = *(const short8*)(cs + (mt*16 + lr)*72 + lg*8);
            short8 a1 = *(const short8*)(cs + (mt*16 + lr)*72 + 32 + lg*8);
            f32x4 accP = {0.f,0.f,0.f,0.f}, accQ = {0.f,0.f,0.f,0.f};
            accP = mfma32(a0, xf[0][0], accP);
            accP = mfma32(a1, xf[0][1], accP);
            accQ = mfma32(a0, xf[1][0], accQ);
            accQ = mfma32(a1, xf[1][1], accQ);
#pragma unroll
            for (int j = 0; j < 4; ++j) {
                float e1 = __expf(2.f*accP[j]);
                float e2 = __expf(2.f*accQ[j]);
                float p = e1*izp_s[j], q = e2*izq_s[j];
                float ss = p + q;
                cross = fmaf(ss, __logf(fmaf(0.5f, ss, 1e-12f)), cross);
                plds[rS[j]*40        + lmt*16 + mS[j]] = f2bf(e1);
                plds[(16 + rS[j])*40 + lmt*16 + mS[j]] = f2bf(e2);
            }
        }
        // O = P*C, K = 32 (this wave's code half within the tile)
        {
            short8 pA = *(const short8*)(plds + lr*40        + lg*8);
            short8 qA = *(const short8*)(plds + (16 + lr)*40 + lg*8);
#pragma unroll
            for (int dt = 0; dt < 3; ++dt) {
                short8 cB = *(const short8*)(ct + (dt*16 + lr)*72 + chw*32 + lg*8);
                Op[dt] = mfma32(pA, cB, Op[dt]);
                Oq[dt] = mfma32(qA, cB, Oq[dt]);
            }
        }
        __syncthreads();
    }

    // ---------------- epilogue: cross reduce, O combine, JSD, store ----------------
#pragma unroll
    for (int off = 1; off < 64; off <<= 1) cross += __shfl_xor(cross, off);
    if (lane == 0) misc[wv] = cross;

    if (chw == 1) {   // write O partial to obuf (reuses cs/ct region)
#pragma unroll
        for (int dt = 0; dt < 3; ++dt)
#pragma unroll
            for (int j = 0; j < 4; ++j) {
                obuf[(rg*32 +      mS[j])*48 + dt*16 + rS[j]] = Op[dt][j];
                obuf[(rg*32 + 16 + mS[j])*48 + dt*16 + rS[j]] = Oq[dt][j];
            }
    }
    __syncthreads();

    if (tid == 0) {
        float es = 0.f;
        for (int r = 0; r < 64; ++r) es += entP[r] + entQ[r];
        float cr = 0.f;
        for (int w = 0; w < 8; ++w) cr += misc[w];
        atomicAdd(Out + JSD_IDX, (es - cr) * (0.5f/32768.f));
    }

    if (chw == 0) {   // combine halves, normalize, store at measured coords
#pragma unroll
        for (int dt = 0; dt < 3; ++dt)
#pragma unroll
            for (int j = 0; j < 4; ++j) {
                int xr = mS[j];
                int np = pg*64 + rg*16 + xr;
                int nq = np + 4096;
                int chc = k*48 + dt*16 + rS[j];
                float vP = (Op[dt][j] + obuf[(rg*32 +      xr)*48 + dt*16 + rS[j]]) * ipzP[rg*16 + xr];
                float vQ = (Oq[dt][j] + obuf[(rg*32 + 16 + xr)*48 + dt*16 + rS[j]]) * ipzQ[rg*16 + xr];
                Out[(size_t)(np >> 10)*Z_BCH + (size_t)chc*1024 + (np & 1023)] = vP;
                Out[(size_t)(nq >> 10)*Z_BCH + (size_t)chc*1024 + (nq & 1023)] = vQ;
            }
    }
}

extern "C" void kernel_launch(void* const* d_in, const int* in_sizes, int n_in,
                              void* d_out, int out_size, void* d_ws, size_t ws_size,
                              hipStream_t stream)
{
    const float* z = (const float*)d_in[0];
    const float* C = (const float*)d_in[1];
    float* out = (float*)d_out;

    hipMemsetAsync(out + JSD_IDX, 0, sizeof(float), stream);

    // 64 pair-groups (64 pairs each) x 8 subspaces; 512 threads (8 waves)
    pq_mfb8<<<dim3(512), dim3(512), 0, stream>>>(z, C, out);
}

// Round 15
// 152.784 us; speedup vs baseline: 1.3938x; 1.3938x over previous
//
#include <hip/hip_runtime.h>

// Soft product quantizer — builtin-MFMA, probe-calibrated, double-buffered.
// z:(8,384,32,32) f32, C:(2048,384) f32. 4096 pairs (n,n+4096) x K=8, d=48, M=2048.
// s = 2<x,c> - |c|^2 (x^2 cancels; |s| small -> no max-subtract).
// Probe MFMAs label every D-slot (mS = A-row, rS = B-col label): exact under
// ANY bijective layout since real GEMMs use the same A/B addressing.
// Pass1: S -> Z,T (LDS atomics keyed rS). Pass2: S again -> P scatter at
// measured coords -> O = P*C (same recipe) -> store at (mS, dt*16+rS).
// NEW: reg-staged double-buffered tiles (T14): LOADREG issues globals early,
// SWRITE lands them next iteration; ONE barrier per tile. c2 from staged regs
// via dbuf partials. Probe-conditional packed plds write (b64 vs 4x b16).

typedef __attribute__((ext_vector_type(8))) short short8;
typedef __attribute__((ext_vector_type(4))) float f32x4;

#define Z_BCH   (384*1024)
#define JSD_IDX 3145728

__device__ __forceinline__ f32x4 mfma32(short8 a, short8 b, f32x4 c) {
    return __builtin_amdgcn_mfma_f32_16x16x32_bf16(a, b, c, 0, 0, 0);
}
__device__ __forceinline__ unsigned short f2bf(float x) {
    unsigned u = __float_as_uint(x);
    u += 0x7FFF + ((u >> 16) & 1);          // RNE
    return (unsigned short)(u >> 16);
}
__device__ __forceinline__ unsigned pk2bf(float a, float b) {
    return (unsigned)f2bf(a) | ((unsigned)f2bf(b) << 16);
}
__device__ __forceinline__ float bf2f(unsigned short h) {
    return __uint_as_float(((unsigned)h) << 16);
}

// LDS (bytes):
//  cs  [2][64][72] u16 @0      (18432)  codes: d0..47, 48/49=-c2/2, 50..63=0
//  ct  [2][48][72] u16 @18432  (13824)  C^T [d][m]
//  plds [8][32][40] u16 @32256 (20480)  per-wave P (16p+16q x 32 codes)
//  c2p [2][64][4] f32 @52736   (2048)   staged |c|^2 partials
//  @54784 ztP[64] ttP ztQ ttQ | @55808 ipzP ipzQ | @56320 entP entQ
//  @56832 misc[8] -> 56864 total
//  overlays: xs [128][72] u16 @0 (prologue) | obuf [4][32][48] f32 @0 (epilogue)
__global__ __launch_bounds__(512, 4)
void pq_db(const float* __restrict__ Zin, const float* __restrict__ Cb,
           float* __restrict__ Out)
{
    __shared__ __align__(16) unsigned char smem[56864];
    unsigned short* cs  = (unsigned short*)smem;               // [2][64][72]
    unsigned short* ctb = (unsigned short*)(smem + 18432);     // [2][48][72]
    unsigned short* xs  = (unsigned short*)smem;
    float* c2p  = (float*)(smem + 52736);                      // [2][64][4]
    float* ztP  = (float*)(smem + 54784);
    float* ttP  = (float*)(smem + 55040);
    float* ztQ  = (float*)(smem + 55296);
    float* ttQ  = (float*)(smem + 55552);
    float* ipzP = (float*)(smem + 55808);
    float* ipzQ = (float*)(smem + 56064);
    float* entP = (float*)(smem + 56320);
    float* entQ = (float*)(smem + 56576);
    float* misc = (float*)(smem + 56832);
    float* obuf = (float*)smem;                                // [4][32][48] epilogue

    const int tid  = threadIdx.x;
    const int lane = tid & 63;
    const int wv   = tid >> 6;          // 0..7
    const int rg   = wv & 3;            // pair-row group (16 pairs)
    const int chw  = wv >> 2;           // code half: mt in {2chw, 2chw+1}
    const int lr   = lane & 15;
    const int lg   = lane >> 4;
    const int pg   = blockIdx.x & 63;
    const int k    = blockIdx.x >> 6;

    unsigned short* plds = (unsigned short*)(smem + 32256 + wv*2560);   // [32][40]

    // ---------- layout probes ----------
    short8 av, on;
#pragma unroll
    for (int i = 0; i < 8; ++i) { av[i] = (short)f2bf((float)lr); on[i] = (short)0x3F80; }
    f32x4 zf4 = {0.f,0.f,0.f,0.f};
    f32x4 dm = mfma32(av, on, zf4);     // slot j -> A-row label
    f32x4 dr = mfma32(on, av, zf4);     // slot j -> B-col label
    int mS[4], rS[4];
#pragma unroll
    for (int j = 0; j < 4; ++j) {
        mS[j] = ((int)(dm[j]*0.03125f + 0.5f)) & 15;
        rS[j] = ((int)(dr[j]*0.03125f + 0.5f)) & 15;
    }
    const bool packOK = __all(mS[1] == mS[0]+1 && mS[2] == mS[0]+2 && mS[3] == mS[0]+3
                              && rS[1] == rS[0] && rS[2] == rS[0] && rS[3] == rS[0]);

    // ---------- prologue: zero cs (incl pad cols) + stats; x -> xs -> regs ----------
    for (int i = tid; i < 4608; i += 512) ((unsigned*)smem)[i] = 0u;
    if (tid < 256) ((float*)(smem + 54784))[tid] = 0.f;
    __syncthreads();
    for (int i = tid; i < 6144; i += 512) {
        int row = i & 127, d = i >> 7;
        int n = pg*64 + (row & 63) + ((row & 64) ? 4096 : 0);
        xs[row*72 + d] = f2bf(Zin[(size_t)(n >> 10)*Z_BCH + (k*48 + d)*1024 + (n & 1023)]);
    }
    if (tid < 128) { xs[tid*72 + 48] = 0x3F80; xs[tid*72 + 49] = 0x3F80; }
    __syncthreads();
    short8 xf[2][2];
#pragma unroll
    for (int kh = 0; kh < 2; ++kh) {
        xf[0][kh] = *(const short8*)(xs + (rg*16 + lr)*72 + kh*32 + lg*8);
        xf[1][kh] = *(const short8*)(xs + (64 + rg*16 + lr)*72 + kh*32 + lg*8);
    }
    __syncthreads();

    // ---------- staging machinery (dbuf, reg-staged) ----------
    const int sm = tid & 63, p8 = (tid >> 6) & 3;
    const bool lowHalf = (tid < 256);
    float4 va, vb, vc;

#define LOADREG(m0, doCT) do {                                                \
        if (lowHalf || (doCT)) {                                              \
            const float4* crow = (const float4*)(Cb + (size_t)((m0) + sm)*384 + k*48); \
            va = crow[p8*3+0]; vb = crow[p8*3+1]; vc = crow[p8*3+2];          \
        } } while (0)

#define C2WRITE(b) do {                                                       \
        if (lowHalf) {                                                        \
            float c2 = va.x*va.x + va.y*va.y + va.z*va.z + va.w*va.w          \
                     + vb.x*vb.x + vb.y*vb.y + vb.z*vb.z + vb.w*vb.w          \
                     + vc.x*vc.x + vc.y*vc.y + vc.z*vc.z + vc.w*vc.w;         \
            c2p[(b)*256 + sm*4 + p8] = c2;                                    \
        } } while (0)

#define SWRITE(b, doCT) do {                                                  \
        if (lowHalf) {                                                        \
            unsigned short* rw = cs + (b)*4608 + sm*72 + p8*12;               \
            *(uint2*)(rw)     = make_uint2(pk2bf(va.x,va.y), pk2bf(va.z,va.w)); \
            *(uint2*)(rw + 4) = make_uint2(pk2bf(vb.x,vb.y), pk2bf(vb.z,vb.w)); \
            *(uint2*)(rw + 8) = make_uint2(pk2bf(vc.x,vc.y), pk2bf(vc.z,vc.w)); \
            if (tid < 64) {                                                   \
                float c2 = c2p[(b)*256 + tid*4+0] + c2p[(b)*256 + tid*4+1]    \
                         + c2p[(b)*256 + tid*4+2] + c2p[(b)*256 + tid*4+3];   \
                float mh = -0.5f*c2;                                          \
                unsigned short hi = f2bf(mh);                                 \
                unsigned short lo = f2bf(mh - bf2f(hi));                      \
                *(unsigned*)(cs + (b)*4608 + tid*72 + 48) =                   \
                    (unsigned)hi | ((unsigned)lo << 16);                      \
            }                                                                 \
        } else if (doCT) {                                                    \
            unsigned short* bs = ctb + (b)*3456;                              \
            const int d0 = p8*12;                                             \
            bs[(d0+ 0)*72+sm] = f2bf(va.x);  bs[(d0+ 1)*72+sm] = f2bf(va.y);  \
            bs[(d0+ 2)*72+sm] = f2bf(va.z);  bs[(d0+ 3)*72+sm] = f2bf(va.w);  \
            bs[(d0+ 4)*72+sm] = f2bf(vb.x);  bs[(d0+ 5)*72+sm] = f2bf(vb.y);  \
            bs[(d0+ 6)*72+sm] = f2bf(vb.z);  bs[(d0+ 7)*72+sm] = f2bf(vb.w);  \
            bs[(d0+ 8)*72+sm] = f2bf(vc.x);  bs[(d0+ 9)*72+sm] = f2bf(vc.y);  \
            bs[(d0+10)*72+sm] = f2bf(vc.z);  bs[(d0+11)*72+sm] = f2bf(vc.w);  \
        } } while (0)

    // ================= pass 1: softmax stats =================
    float zp[4]={0,0,0,0}, tp[4]={0,0,0,0}, zq[4]={0,0,0,0}, tq[4]={0,0,0,0};

    LOADREG(0, false); C2WRITE(0);
    __syncthreads();
    SWRITE(0, false);
    LOADREG(64, false); C2WRITE(1);
    __syncthreads();

#pragma unroll 1
    for (int t = 0; t < 32; ++t) {
        if (t < 31) SWRITE((t+1)&1, false);
        if (t < 30) LOADREG((t+2)*64, false);
        const unsigned short* cst = cs + (t&1)*4608;
#pragma unroll
        for (int lmt = 0; lmt < 2; ++lmt) {
            const int mt = chw*2 + lmt;
            short8 a0 = *(const short8*)(cst + (mt*16 + lr)*72 + lg*8);
            short8 a1 = *(const short8*)(cst + (mt*16 + lr)*72 + 32 + lg*8);
            f32x4 accP = {0.f,0.f,0.f,0.f}, accQ = {0.f,0.f,0.f,0.f};
            accP = mfma32(a0, xf[0][0], accP);
            accP = mfma32(a1, xf[0][1], accP);
            accQ = mfma32(a0, xf[1][0], accQ);
            accQ = mfma32(a1, xf[1][1], accQ);
#pragma unroll
            for (int j = 0; j < 4; ++j) {
                float sp = 2.f*accP[j], sq = 2.f*accQ[j];
                float e1 = __expf(sp), e2 = __expf(sq);
                zp[j] += e1; tp[j] = fmaf(e1, sp, tp[j]);
                zq[j] += e2; tq[j] = fmaf(e2, sq, tq[j]);
            }
        }
        if (t < 30) C2WRITE(t&1);
        __syncthreads();
    }

    // per-row totals via LDS atomics keyed by measured rS
#pragma unroll
    for (int j = 0; j < 4; ++j) {
        int r = rg*16 + rS[j];
        atomicAdd(ztP + r, zp[j]); atomicAdd(ttP + r, tp[j]);
        atomicAdd(ztQ + r, zq[j]); atomicAdd(ttQ + r, tq[j]);
    }
    __syncthreads();
    if (tid < 64) {
        float z1 = ztP[tid], t1 = ttP[tid];
        float z2 = ztQ[tid], t2 = ttQ[tid];
        float i1 = 1.f/z1, i2 = 1.f/z2;
        ipzP[tid] = i1; entP[tid] = t1*i1 - __logf(z1);
        ipzQ[tid] = i2; entQ[tid] = t2*i2 - __logf(z2);
    }
    __syncthreads();
    float izp_s[4], izq_s[4];
#pragma unroll
    for (int j = 0; j < 4; ++j) {
        izp_s[j] = ipzP[rg*16 + rS[j]];
        izq_s[j] = ipzQ[rg*16 + rS[j]];
    }

    // ================= pass 2: S again, P scatter, O-MFMA, cross =================
    f32x4 Op[3], Oq[3];
#pragma unroll
    for (int dt = 0; dt < 3; ++dt) { Op[dt] = (f32x4){0.f,0.f,0.f,0.f}; Oq[dt] = (f32x4){0.f,0.f,0.f,0.f}; }
    float cross = 0.f;

    LOADREG(0, true); C2WRITE(0);
    __syncthreads();
    SWRITE(0, true);
    LOADREG(64, true); C2WRITE(1);
    __syncthreads();

#pragma unroll 1
    for (int t = 0; t < 32; ++t) {
        if (t < 31) SWRITE((t+1)&1, true);
        if (t < 30) LOADREG((t+2)*64, true);
        const unsigned short* cst = cs + (t&1)*4608;
        const unsigned short* ctt = ctb + (t&1)*3456;
#pragma unroll
        for (int lmt = 0; lmt < 2; ++lmt) {
            const int mt = chw*2 + lmt;
            short8 a0 = *(const short8*)(cst + (mt*16 + lr)*72 + lg*8);
            short8 a1 = *(const short8*)(cst + (mt*16 + lr)*72 + 32 + lg*8);
            f32x4 accP = {0.f,0.f,0.f,0.f}, accQ = {0.f,0.f,0.f,0.f};
            accP = mfma32(a0, xf[0][0], accP);
            accP = mfma32(a1, xf[0][1], accP);
            accQ = mfma32(a0, xf[1][0], accQ);
            accQ = mfma32(a1, xf[1][1], accQ);
            float e1a[4], e2a[4];
#pragma unroll
            for (int j = 0; j < 4; ++j) {
                float e1 = __expf(2.f*accP[j]);
                float e2 = __expf(2.f*accQ[j]);
                e1a[j] = e1; e2a[j] = e2;
                float p = e1*izp_s[j], q = e2*izq_s[j];
                float ss = p + q;
                cross = fmaf(ss, __logf(fmaf(0.5f, ss, 1e-12f)), cross);
            }
            if (packOK) {   // m89-pattern: one b64 per row instead of 4 b16
                *(uint2*)(plds + rS[0]*40        + lmt*16 + mS[0]) =
                    make_uint2(pk2bf(e1a[0], e1a[1]), pk2bf(e1a[2], e1a[3]));
                *(uint2*)(plds + (16 + rS[0])*40 + lmt*16 + mS[0]) =
                    make_uint2(pk2bf(e2a[0], e2a[1]), pk2bf(e2a[2], e2a[3]));
            } else {
#pragma unroll
                for (int j = 0; j < 4; ++j) {
                    plds[rS[j]*40        + lmt*16 + mS[j]] = f2bf(e1a[j]);
                    plds[(16 + rS[j])*40 + lmt*16 + mS[j]] = f2bf(e2a[j]);
                }
            }
        }
        // O = P*C, K=32 (wave's code half), wave-local plds
        {
            short8 pA = *(const short8*)(plds + lr*40        + lg*8);
            short8 qA = *(const short8*)(plds + (16 + lr)*40 + lg*8);
#pragma unroll
            for (int dt = 0; dt < 3; ++dt) {
                short8 cB = *(const short8*)(ctt + (dt*16 + lr)*72 + chw*32 + lg*8);
                Op[dt] = mfma32(pA, cB, Op[dt]);
                Oq[dt] = mfma32(qA, cB, Oq[dt]);
            }
        }
        if (t < 30) C2WRITE(t&1);
        __syncthreads();
    }

    // ---------------- epilogue ----------------
#pragma unroll
    for (int off = 1; off < 64; off <<= 1) cross += __shfl_xor(cross, off);
    if (lane == 0) misc[wv] = cross;

    if (chw == 1) {   // O partial to obuf (overlays dead cs/ct)
#pragma unroll
        for (int dt = 0; dt < 3; ++dt)
#pragma unroll
            for (int j = 0; j < 4; ++j) {
                obuf[(rg*32 +      mS[j])*48 + dt*16 + rS[j]] = Op[dt][j];
                obuf[(rg*32 + 16 + mS[j])*48 + dt*16 + rS[j]] = Oq[dt][j];
            }
    }
    __syncthreads();

    if (tid == 0) {
        float es = 0.f;
        for (int r = 0; r < 64; ++r) es += entP[r] + entQ[r];
        float cr = 0.f;
        for (int w = 0; w < 8; ++w) cr += misc[w];
        atomicAdd(Out + JSD_IDX, (es - cr) * (0.5f/32768.f));
    }

    if (chw == 0) {   // combine halves, normalize, store at measured coords
#pragma unroll
        for (int dt = 0; dt < 3; ++dt)
#pragma unroll
            for (int j = 0; j < 4; ++j) {
                int xr = mS[j];
                int np = pg*64 + rg*16 + xr;
                int nq = np + 4096;
                int chc = k*48 + dt*16 + rS[j];
                float vP = (Op[dt][j] + obuf[(rg*32 +      xr)*48 + dt*16 + rS[j]]) * ipzP[rg*16 + xr];
                float vQ = (Oq[dt][j] + obuf[(rg*32 + 16 + xr)*48 + dt*16 + rS[j]]) * ipzQ[rg*16 + xr];
                Out[(size_t)(np >> 10)*Z_BCH + (size_t)chc*1024 + (np & 1023)] = vP;
                Out[(size_t)(nq >> 10)*Z_BCH + (size_t)chc*1024 + (nq & 1023)] = vQ;
            }
    }
}

extern "C" void kernel_launch(void* const* d_in, const int* in_sizes, int n_in,
                              void* d_out, int out_size, void* d_ws, size_t ws_size,
                              hipStream_t stream)
{
    const float* z = (const float*)d_in[0];
    const float* C = (const float*)d_in[1];
    float* out = (float*)d_out;

    hipMemsetAsync(out + JSD_IDX, 0, sizeof(float), stream);

    // 64 pair-groups (64 pairs each) x 8 subspaces; 512 threads (8 waves)
    pq_db<<<dim3(512), dim3(512), 0, stream>>>(z, C, out);
}

// Round 16
// 146.613 us; speedup vs baseline: 1.4524x; 1.0421x over previous
//
#include <hip/hip_runtime.h>

// Soft product quantizer — builtin-MFMA, probe-calibrated, double-buffered,
// PRECOMPUTED TILES: a prep kernel converts C once into ws as bf16 tiles in
// the exact LDS layouts (cs: [m][72] with -c2/2 at cols 48/49, zeros 50..63;
// ct: transposed [d][72] per 64-code tile). Main-loop staging = linear uint4
// copies (no conversions, no c2, conflict-free writes).
// Math identical to R13-15: s = 2<x,c> - |c|^2; pass1 Z,T; pass2 P->O, cross.
// Probe MFMAs label D-slots (mS=A-row, rS=B-col) -> correct under any
// bijective fragment layout.

typedef __attribute__((ext_vector_type(8))) short short8;
typedef __attribute__((ext_vector_type(4))) float f32x4;

#define Z_BCH   (384*1024)
#define JSD_IDX 3145728
#define CS_TILE 9216          // 64 rows * 72 u16 * 2B
#define CT_TILE 6912          // 48 rows * 72 u16 * 2B
#define CT_OFF  (8*32*CS_TILE)   // 2359296

__device__ __forceinline__ f32x4 mfma32(short8 a, short8 b, f32x4 c) {
    return __builtin_amdgcn_mfma_f32_16x16x32_bf16(a, b, c, 0, 0, 0);
}
__device__ __forceinline__ unsigned short f2bf(float x) {
    unsigned u = __float_as_uint(x);
    u += 0x7FFF + ((u >> 16) & 1);          // RNE
    return (unsigned short)(u >> 16);
}
__device__ __forceinline__ unsigned pk2bf(float a, float b) {
    return (unsigned)f2bf(a) | ((unsigned)f2bf(b) << 16);
}
__device__ __forceinline__ float bf2f(unsigned short h) {
    return __uint_as_float(((unsigned)h) << 16);
}

// ===================== prep: C -> bf16 tiles in ws =====================
// grid 256 blocks: k = b>>5, t = b&31; 256 threads: sm = tid&63, p8 = tid>>6.
__global__ __launch_bounds__(256)
void pq_prep(const float* __restrict__ Cb, unsigned char* __restrict__ ws)
{
    const int tid = threadIdx.x;
    const int k   = blockIdx.x >> 5;
    const int t   = blockIdx.x & 31;
    const int sm  = tid & 63, p8 = tid >> 6;
    const int m   = t*64 + sm;

    unsigned short* csT = (unsigned short*)(ws + (size_t)(k*32 + t)*CS_TILE);
    unsigned short* ctT = (unsigned short*)(ws + CT_OFF + (size_t)(k*32 + t)*CT_TILE);

    const float4* crow = (const float4*)(Cb + (size_t)m*384 + k*48);
    float4 va = crow[p8*3+0], vb = crow[p8*3+1], vc = crow[p8*3+2];
    const int d0 = p8*12;
    // cs rows (code-major)
    *(uint2*)(csT + sm*72 + d0 + 0) = make_uint2(pk2bf(va.x,va.y), pk2bf(va.z,va.w));
    *(uint2*)(csT + sm*72 + d0 + 4) = make_uint2(pk2bf(vb.x,vb.y), pk2bf(vb.z,vb.w));
    *(uint2*)(csT + sm*72 + d0 + 8) = make_uint2(pk2bf(vc.x,vc.y), pk2bf(vc.z,vc.w));
    // ct rows (dim-major, transposed)
    ctT[(d0+ 0)*72+sm] = f2bf(va.x);  ctT[(d0+ 1)*72+sm] = f2bf(va.y);
    ctT[(d0+ 2)*72+sm] = f2bf(va.z);  ctT[(d0+ 3)*72+sm] = f2bf(va.w);
    ctT[(d0+ 4)*72+sm] = f2bf(vb.x);  ctT[(d0+ 5)*72+sm] = f2bf(vb.y);
    ctT[(d0+ 6)*72+sm] = f2bf(vb.z);  ctT[(d0+ 7)*72+sm] = f2bf(vb.w);
    ctT[(d0+ 8)*72+sm] = f2bf(vc.x);  ctT[(d0+ 9)*72+sm] = f2bf(vc.y);
    ctT[(d0+10)*72+sm] = f2bf(vc.z);  ctT[(d0+11)*72+sm] = f2bf(vc.w);
    // pad cols 48..63: -c2/2 (hi+lo) then zeros
    if (tid < 64) {
        const float4* cr2 = (const float4*)(Cb + (size_t)(t*64 + tid)*384 + k*48);
        float c2 = 0.f;
#pragma unroll
        for (int i = 0; i < 12; ++i) {
            float4 v = cr2[i];
            c2 += v.x*v.x + v.y*v.y + v.z*v.z + v.w*v.w;
        }
        float mh = -0.5f*c2;
        unsigned short hi = f2bf(mh);
        unsigned short lo = f2bf(mh - bf2f(hi));
        *(uint2*)(csT + tid*72 + 48) = make_uint2((unsigned)hi | ((unsigned)lo << 16), 0u);
        *(uint2*)(csT + tid*72 + 52) = make_uint2(0u, 0u);
        *(uint2*)(csT + tid*72 + 56) = make_uint2(0u, 0u);
        *(uint2*)(csT + tid*72 + 60) = make_uint2(0u, 0u);
    }
}

// ===================== main kernel =====================
// LDS: cs [2][9216] @0 | ct [2][6912] @18432 | plds [8][32][40]u16 @32256
// stats @52736.. (zt/tt P/Q 4x256B) | ipz @53760/54016 | ent @54272/54528
// misc @54784 -> 54816 total. Overlays: xs[128][72]u16 @0 (prologue),
// obuf[4][32][48]f32 @0 (epilogue, 24576B < cs+ct).
__global__ __launch_bounds__(512, 4)
void pq_pc(const float* __restrict__ Zin, const unsigned char* __restrict__ ws,
           float* __restrict__ Out)
{
    __shared__ __align__(16) unsigned char smem[54816];
    unsigned short* cs  = (unsigned short*)smem;
    unsigned short* ctb = (unsigned short*)(smem + 18432);
    unsigned short* xs  = (unsigned short*)smem;
    float* ztP  = (float*)(smem + 52736);
    float* ttP  = (float*)(smem + 52992);
    float* ztQ  = (float*)(smem + 53248);
    float* ttQ  = (float*)(smem + 53504);
    float* ipzP = (float*)(smem + 53760);
    float* ipzQ = (float*)(smem + 54016);
    float* entP = (float*)(smem + 54272);
    float* entQ = (float*)(smem + 54528);
    float* misc = (float*)(smem + 54784);
    float* obuf = (float*)smem;

    const int tid  = threadIdx.x;
    const int lane = tid & 63;
    const int wv   = tid >> 6;
    const int rg   = wv & 3;
    const int chw  = wv >> 2;
    const int lr   = lane & 15;
    const int lg   = lane >> 4;
    const int pg   = blockIdx.x & 63;
    const int k    = blockIdx.x >> 6;

    unsigned short* plds = (unsigned short*)(smem + 32256 + wv*2560);   // [32][40]
    const unsigned char* csg = ws + (size_t)(k*32)*CS_TILE;
    const unsigned char* ctg = ws + CT_OFF + (size_t)(k*32)*CT_TILE;

    // ---------- layout probes ----------
    short8 av, on;
#pragma unroll
    for (int i = 0; i < 8; ++i) { av[i] = (short)f2bf((float)lr); on[i] = (short)0x3F80; }
    f32x4 zf4 = {0.f,0.f,0.f,0.f};
    f32x4 dmv = mfma32(av, on, zf4);
    f32x4 drv = mfma32(on, av, zf4);
    int mS[4], rS[4];
#pragma unroll
    for (int j = 0; j < 4; ++j) {
        mS[j] = ((int)(dmv[j]*0.03125f + 0.5f)) & 15;
        rS[j] = ((int)(drv[j]*0.03125f + 0.5f)) & 15;
    }
    const bool packOK = __all(mS[1] == mS[0]+1 && mS[2] == mS[0]+2 && mS[3] == mS[0]+3
                              && rS[1] == rS[0] && rS[2] == rS[0] && rS[3] == rS[0]);

    // ---------- prologue: x -> xs -> register B-frags ----------
    for (int i = tid; i < 4608; i += 512) ((unsigned*)smem)[i] = 0u;   // zero xs
    if (tid < 256) ((float*)(smem + 52736))[tid] = 0.f;                // zt/tt
    __syncthreads();
    for (int i = tid; i < 6144; i += 512) {
        int row = i & 127, d = i >> 7;
        int n = pg*64 + (row & 63) + ((row & 64) ? 4096 : 0);
        xs[row*72 + d] = f2bf(Zin[(size_t)(n >> 10)*Z_BCH + (k*48 + d)*1024 + (n & 1023)]);
    }
    if (tid < 128) { xs[tid*72 + 48] = 0x3F80; xs[tid*72 + 49] = 0x3F80; }
    __syncthreads();
    short8 xf[2][2];
#pragma unroll
    for (int kh = 0; kh < 2; ++kh) {
        xf[0][kh] = *(const short8*)(xs + (rg*16 + lr)*72 + kh*32 + lg*8);
        xf[1][kh] = *(const short8*)(xs + (64 + rg*16 + lr)*72 + kh*32 + lg*8);
    }
    __syncthreads();

    // ---------- staging: pure linear copies ----------
    uint4 r0, r1, r2;
#define LOADREG(t, doCT) do {                                                 \
        const unsigned char* _c = csg + (size_t)(t)*CS_TILE;                  \
        r0 = *(const uint4*)(_c + tid*16);                                    \
        if (tid < 64) r1 = *(const uint4*)(_c + 8192 + tid*16);               \
        if ((doCT) && tid < 432)                                              \
            r2 = *(const uint4*)(ctg + (size_t)(t)*CT_TILE + tid*16);         \
    } while (0)

#define SWRITE(b, doCT) do {                                                  \
        *(uint4*)(smem + (b)*CS_TILE + tid*16) = r0;                          \
        if (tid < 64) *(uint4*)(smem + (b)*CS_TILE + 8192 + tid*16) = r1;     \
        if ((doCT) && tid < 432)                                              \
            *(uint4*)(smem + 18432 + (b)*CT_TILE + tid*16) = r2;              \
    } while (0)

    // ================= pass 1: softmax stats =================
    float zp[4]={0,0,0,0}, tp[4]={0,0,0,0}, zq[4]={0,0,0,0}, tq[4]={0,0,0,0};

    LOADREG(0, false);
    SWRITE(0, false);
    LOADREG(1, false);
    __syncthreads();

#pragma unroll 1
    for (int t = 0; t < 32; ++t) {
        if (t < 31) SWRITE((t+1)&1, false);
        if (t < 30) LOADREG(t+2, false);
        const unsigned short* cst = cs + (t&1)*4608;
#pragma unroll
        for (int lmt = 0; lmt < 2; ++lmt) {
            const int mt = chw*2 + lmt;
            short8 a0 = *(const short8*)(cst + (mt*16 + lr)*72 + lg*8);
            short8 a1 = *(const short8*)(cst + (mt*16 + lr)*72 + 32 + lg*8);
            f32x4 accP = {0.f,0.f,0.f,0.f}, accQ = {0.f,0.f,0.f,0.f};
            accP = mfma32(a0, xf[0][0], accP);
            accP = mfma32(a1, xf[0][1], accP);
            accQ = mfma32(a0, xf[1][0], accQ);
            accQ = mfma32(a1, xf[1][1], accQ);
#pragma unroll
            for (int j = 0; j < 4; ++j) {
                float sp = 2.f*accP[j], sq = 2.f*accQ[j];
                float e1 = __expf(sp), e2 = __expf(sq);
                zp[j] += e1; tp[j] = fmaf(e1, sp, tp[j]);
                zq[j] += e2; tq[j] = fmaf(e2, sq, tq[j]);
            }
        }
        __syncthreads();
    }

#pragma unroll
    for (int j = 0; j < 4; ++j) {
        int r = rg*16 + rS[j];
        atomicAdd(ztP + r, zp[j]); atomicAdd(ttP + r, tp[j]);
        atomicAdd(ztQ + r, zq[j]); atomicAdd(ttQ + r, tq[j]);
    }
    __syncthreads();
    if (tid < 64) {
        float z1 = ztP[tid], t1 = ttP[tid];
        float z2 = ztQ[tid], t2 = ttQ[tid];
        float i1 = 1.f/z1, i2 = 1.f/z2;
        ipzP[tid] = i1; entP[tid] = t1*i1 - __logf(z1);
        ipzQ[tid] = i2; entQ[tid] = t2*i2 - __logf(z2);
    }
    __syncthreads();
    float izp_s[4], izq_s[4];
#pragma unroll
    for (int j = 0; j < 4; ++j) {
        izp_s[j] = ipzP[rg*16 + rS[j]];
        izq_s[j] = ipzQ[rg*16 + rS[j]];
    }

    // ================= pass 2: P scatter, O-MFMA, cross =================
    f32x4 Op[3], Oq[3];
#pragma unroll
    for (int dt = 0; dt < 3; ++dt) { Op[dt] = (f32x4){0.f,0.f,0.f,0.f}; Oq[dt] = (f32x4){0.f,0.f,0.f,0.f}; }
    float cross = 0.f;

    LOADREG(0, true);
    SWRITE(0, true);
    LOADREG(1, true);
    __syncthreads();

#pragma unroll 1
    for (int t = 0; t < 32; ++t) {
        if (t < 31) SWRITE((t+1)&1, true);
        if (t < 30) LOADREG(t+2, true);
        const unsigned short* cst = cs + (t&1)*4608;
        const unsigned short* ctt = ctb + (t&1)*3456;
#pragma unroll
        for (int lmt = 0; lmt < 2; ++lmt) {
            const int mt = chw*2 + lmt;
            short8 a0 = *(const short8*)(cst + (mt*16 + lr)*72 + lg*8);
            short8 a1 = *(const short8*)(cst + (mt*16 + lr)*72 + 32 + lg*8);
            f32x4 accP = {0.f,0.f,0.f,0.f}, accQ = {0.f,0.f,0.f,0.f};
            accP = mfma32(a0, xf[0][0], accP);
            accP = mfma32(a1, xf[0][1], accP);
            accQ = mfma32(a0, xf[1][0], accQ);
            accQ = mfma32(a1, xf[1][1], accQ);
            float e1a[4], e2a[4];
#pragma unroll
            for (int j = 0; j < 4; ++j) {
                float e1 = __expf(2.f*accP[j]);
                float e2 = __expf(2.f*accQ[j]);
                e1a[j] = e1; e2a[j] = e2;
                float p = e1*izp_s[j], q = e2*izq_s[j];
                float ss = p + q;
                cross = fmaf(ss, __logf(fmaf(0.5f, ss, 1e-12f)), cross);
            }
            if (packOK) {
                *(uint2*)(plds + rS[0]*40        + lmt*16 + mS[0]) =
                    make_uint2(pk2bf(e1a[0], e1a[1]), pk2bf(e1a[2], e1a[3]));
                *(uint2*)(plds + (16 + rS[0])*40 + lmt*16 + mS[0]) =
                    make_uint2(pk2bf(e2a[0], e2a[1]), pk2bf(e2a[2], e2a[3]));
            } else {
#pragma unroll
                for (int j = 0; j < 4; ++j) {
                    plds[rS[j]*40        + lmt*16 + mS[j]] = f2bf(e1a[j]);
                    plds[(16 + rS[j])*40 + lmt*16 + mS[j]] = f2bf(e2a[j]);
                }
            }
        }
        {
            short8 pA = *(const short8*)(plds + lr*40        + lg*8);
            short8 qA = *(const short8*)(plds + (16 + lr)*40 + lg*8);
#pragma unroll
            for (int dt = 0; dt < 3; ++dt) {
                short8 cB = *(const short8*)(ctt + (dt*16 + lr)*72 + chw*32 + lg*8);
                Op[dt] = mfma32(pA, cB, Op[dt]);
                Oq[dt] = mfma32(qA, cB, Oq[dt]);
            }
        }
        __syncthreads();
    }

    // ---------------- epilogue ----------------
#pragma unroll
    for (int off = 1; off < 64; off <<= 1) cross += __shfl_xor(cross, off);
    if (lane == 0) misc[wv] = cross;

    if (chw == 1) {
#pragma unroll
        for (int dt = 0; dt < 3; ++dt)
#pragma unroll
            for (int j = 0; j < 4; ++j) {
                obuf[(rg*32 +      mS[j])*48 + dt*16 + rS[j]] = Op[dt][j];
                obuf[(rg*32 + 16 + mS[j])*48 + dt*16 + rS[j]] = Oq[dt][j];
            }
    }
    __syncthreads();

    if (tid == 0) {
        float es = 0.f;
        for (int r = 0; r < 64; ++r) es += entP[r] + entQ[r];
        float cr = 0.f;
        for (int w = 0; w < 8; ++w) cr += misc[w];
        atomicAdd(Out + JSD_IDX, (es - cr) * (0.5f/32768.f));
    }

    if (chw == 0) {
#pragma unroll
        for (int dt = 0; dt < 3; ++dt)
#pragma unroll
            for (int j = 0; j < 4; ++j) {
                int xr = mS[j];
                int np = pg*64 + rg*16 + xr;
                int nq = np + 4096;
                int chc = k*48 + dt*16 + rS[j];
                float vP = (Op[dt][j] + obuf[(rg*32 +      xr)*48 + dt*16 + rS[j]]) * ipzP[rg*16 + xr];
                float vQ = (Oq[dt][j] + obuf[(rg*32 + 16 + xr)*48 + dt*16 + rS[j]]) * ipzQ[rg*16 + xr];
                Out[(size_t)(np >> 10)*Z_BCH + (size_t)chc*1024 + (np & 1023)] = vP;
                Out[(size_t)(nq >> 10)*Z_BCH + (size_t)chc*1024 + (nq & 1023)] = vQ;
            }
    }
}

extern "C" void kernel_launch(void* const* d_in, const int* in_sizes, int n_in,
                              void* d_out, int out_size, void* d_ws, size_t ws_size,
                              hipStream_t stream)
{
    const float* z = (const float*)d_in[0];
    const float* C = (const float*)d_in[1];
    float* out = (float*)d_out;

    hipMemsetAsync(out + JSD_IDX, 0, sizeof(float), stream);

    // one-time C -> bf16 tile image in ws (4.13 MB)
    pq_prep<<<dim3(256), dim3(256), 0, stream>>>(C, (unsigned char*)d_ws);
    // 64 pair-groups (64 pairs each) x 8 subspaces; 512 threads (8 waves)
    pq_pc<<<dim3(512), dim3(512), 0, stream>>>(z, (const unsigned char*)d_ws, out);
}